// Round 6
// baseline (222.555 us; speedup 1.0000x reference)
//
#include <hip/hip_runtime.h>

#define N_E 10000
#define N_KC 2000
#define ALPHA 0.2f

typedef __attribute__((ext_vector_type(8))) short short8;
typedef __attribute__((ext_vector_type(4))) float f32x4;

// ---- static device scratch (fully rewritten every call) ----
__device__ float g_w1a1[256];
__device__ float g_t[2048];
__device__ __align__(16) unsigned short g_W1T_pk[16 * 8 * 512];    // B: W1^T
__device__ __align__(16) unsigned short g_ET_pk[16 * 8 * 512];     // B: E^T
__device__ __align__(16) unsigned short g_rdw_pk[16 * 16 * 512];   // B: rd_w
__device__ __align__(16) unsigned short g_kcWh_pk[16 * 64 * 512];  // B: kcWh^T
// P matrix in MFMA A-fragment layout: [tile][kk][lane][8] bf16.
// 626 tiles of 16 rows (tile 625 is a never-written, BSS-zero phantom for
// the masked tail of the last 32-row GEMM block). 40.4 MB.
__device__ __align__(16) unsigned short g_P_pk[626u * 63 * 512];
__device__ float g_inv[10016];  // 1/softmax-denominator per row

__device__ __forceinline__ unsigned short f2bf(float f) {
  union { float f; unsigned int u; } v; v.f = f;
  unsigned int r = v.u + 0x7FFFu + ((v.u >> 16) & 1u);
  return (unsigned short)(r >> 16);
}

__device__ __forceinline__ void cvt_store4(float4 v, unsigned short* dst) {
  ushort4 o;
  o.x = f2bf(v.x); o.y = f2bf(v.y); o.z = f2bf(v.z); o.w = f2bf(v.w);
  *reinterpret_cast<ushort4*>(dst) = o;
}

// ---- prep: weight packing + w1a1 + zero pads (66 blocks, tiny) ----
__global__ __launch_bounds__(256) void prep_kernel(
    const float* __restrict__ W1, const float* __restrict__ E,
    const float* __restrict__ a, const float* __restrict__ rd_w) {
  int b = blockIdx.x, tid = threadIdx.x;
  if (b < 32) {  // rd_w -> packed B (ct 16 x kt 16)
#pragma unroll
    for (int s2 = 0; s2 < 2; ++s2) {
      int sId = b * 512 + tid + s2 * 256;
      int ct = sId >> 10, rem = sId & 1023;
      int kt = rem >> 6, lane = rem & 63;
      int g = lane >> 4, r = lane & 15;
      const float* src = rd_w + (size_t)(ct * 16 + r) * 512 + kt * 32 + g * 8;
      unsigned short* dst = g_rdw_pk + (size_t)sId * 8;
      cvt_store4(*(const float4*)src, dst);
      cvt_store4(*(const float4*)(src + 4), dst + 4);
    }
  } else if (b < 48) {  // W1^T -> packed B (ct 16 x kt 8)
#pragma unroll
    for (int s2 = 0; s2 < 2; ++s2) {
      int sId = (b - 32) * 512 + tid + s2 * 256;
      int ct = sId >> 9, rem = sId & 511;
      int kt = rem >> 6, lane = rem & 63;
      int g = lane >> 4, r = lane & 15;
      int col = ct * 16 + r, k = kt * 32 + g * 8;
      unsigned short* dst = g_W1T_pk + (size_t)sId * 8;
      ushort4 o0, o1;
      o0.x = f2bf(W1[(k + 0) * 256 + col]); o0.y = f2bf(W1[(k + 1) * 256 + col]);
      o0.z = f2bf(W1[(k + 2) * 256 + col]); o0.w = f2bf(W1[(k + 3) * 256 + col]);
      o1.x = f2bf(W1[(k + 4) * 256 + col]); o1.y = f2bf(W1[(k + 5) * 256 + col]);
      o1.z = f2bf(W1[(k + 6) * 256 + col]); o1.w = f2bf(W1[(k + 7) * 256 + col]);
      *(ushort4*)dst = o0; *(ushort4*)(dst + 4) = o1;
    }
  } else if (b < 64) {  // E^T -> packed B
#pragma unroll
    for (int s2 = 0; s2 < 2; ++s2) {
      int sId = (b - 48) * 512 + tid + s2 * 256;
      int ct = sId >> 9, rem = sId & 511;
      int kt = rem >> 6, lane = rem & 63;
      int g = lane >> 4, r = lane & 15;
      int col = ct * 16 + r, k = kt * 32 + g * 8;
      unsigned short* dst = g_ET_pk + (size_t)sId * 8;
      ushort4 o0, o1;
      o0.x = f2bf(E[(k + 0) * 256 + col]); o0.y = f2bf(E[(k + 1) * 256 + col]);
      o0.z = f2bf(E[(k + 2) * 256 + col]); o0.w = f2bf(E[(k + 3) * 256 + col]);
      o1.x = f2bf(E[(k + 4) * 256 + col]); o1.y = f2bf(E[(k + 5) * 256 + col]);
      o1.z = f2bf(E[(k + 6) * 256 + col]); o1.w = f2bf(E[(k + 7) * 256 + col]);
      *(ushort4*)dst = o0; *(ushort4*)(dst + 4) = o1;
    }
  } else if (b == 64) {  // w1a1
    float acc = 0.f;
    for (int q = 0; q < 64; ++q) {
      float4 wv = *(const float4*)(W1 + (size_t)tid * 256 + q * 4);
      float4 a4 = *(const float4*)(a + q * 4);
      acc += wv.x * a4.x + wv.y * a4.y + wv.z * a4.z + wv.w * a4.w;
    }
    g_w1a1[tid] = acc;
  } else {  // zero pads: kcWh kTiles 62,63 + g_t tail
    for (int idx = tid; idx < 16 * 2 * 512; idx += 256) {
      int ct = idx >> 10, rem = idx & 1023;
      int kt = 62 + (rem >> 9), off = rem & 511;
      g_kcWh_pk[((size_t)ct * 64 + kt) * 512 + off] = 0;
    }
    if (tid < 48) g_t[2000 + tid] = 0.f;
  }
}

// ---- kcWh^T via MFMA (A from f32 kc_h on the fly) + fused t = kcWh@a2 ----
__global__ __launch_bounds__(256) void kc_mfma_kernel(
    const float* __restrict__ kc_h, const float* __restrict__ a) {
  __shared__ float tred[4][4][4];
  int tid = threadIdx.x, lane = tid & 63, w = tid >> 6;
  int r = lane & 15, g = lane >> 4;
  int j0 = blockIdx.x * 16;
  f32x4 acc[4] = {{0.f,0.f,0.f,0.f},{0.f,0.f,0.f,0.f},
                  {0.f,0.f,0.f,0.f},{0.f,0.f,0.f,0.f}};
  for (int kk = 0; kk < 8; ++kk) {
    int k = kk * 32 + g * 8;
    const float* src = kc_h + (size_t)(j0 + r) * 256 + k;
    float4 x0 = *(const float4*)src, x1 = *(const float4*)(src + 4);
    short8 af = {(short)f2bf(x0.x), (short)f2bf(x0.y), (short)f2bf(x0.z),
                 (short)f2bf(x0.w), (short)f2bf(x1.x), (short)f2bf(x1.y),
                 (short)f2bf(x1.z), (short)f2bf(x1.w)};
#pragma unroll
    for (int n = 0; n < 4; ++n) {
      short8 bf = *(const short8*)(g_W1T_pk + ((size_t)(w * 4 + n) * 8 + kk) *
                                                  512 + lane * 8);
      acc[n] = __builtin_amdgcn_mfma_f32_16x16x32_bf16(af, bf, acc[n], 0, 0, 0);
    }
  }
  int j = j0 + g * 4;
  int kt = j >> 5, lsub = ((j >> 3) & 3) * 16 + r, sub = (g & 1) * 4;
#pragma unroll
  for (int n = 0; n < 4; ++n) {
    int ct = w * 4 + n;
    ushort4 o;
    o.x = f2bf(acc[n][0]); o.y = f2bf(acc[n][1]);
    o.z = f2bf(acc[n][2]); o.w = f2bf(acc[n][3]);
    *reinterpret_cast<ushort4*>(
        g_kcWh_pk + ((size_t)ct * 64 + kt) * 512 + lsub * 8 + sub) = o;
  }
  float a2v[4];
#pragma unroll
  for (int n = 0; n < 4; ++n) a2v[n] = a[256 + w * 64 + n * 16 + r];
  float tp[4];
#pragma unroll
  for (int q = 0; q < 4; ++q)
    tp[q] = acc[0][q] * a2v[0] + acc[1][q] * a2v[1] + acc[2][q] * a2v[2] +
            acc[3][q] * a2v[3];
#pragma unroll
  for (int off = 1; off < 16; off <<= 1)
#pragma unroll
    for (int q = 0; q < 4; ++q) tp[q] += __shfl_xor(tp[q], off, 64);
  if (r == 0)
#pragma unroll
    for (int q = 0; q < 4; ++q) tred[w][g][q] = tp[q];
  __syncthreads();
  if (tid < 16)
    g_t[j0 + tid] = tred[0][tid >> 2][tid & 3] + tred[1][tid >> 2][tid & 3] +
                    tred[2][tid >> 2][tid & 3] + tred[3][tid >> 2][tid & 3];
}

// ---- P: streaming generation of the attention matrix, decoupled from GEMM.
// 625 blocks x 16 rows. No MFMA, no inner barriers, max TLP. Writes
// fragment-packed bf16 P (coalesced 1KB stores) + per-row inverse denom.
__global__ __launch_bounds__(256) void p_gen_kernel(
    const float* __restrict__ exh, const int* __restrict__ adj) {
  __shared__ float t_s[2048];
  __shared__ float sv_s[16];
  __shared__ float ds_red[4][16];
  int tid = threadIdx.x, lane = tid & 63, q = tid >> 6;
  int i0 = blockIdx.x * 16;  // 625*16 == 10000 exactly

  // stage t (zero-padded to 2048 by prep)
  ((float4*)t_s)[tid] = ((const float4*)g_t)[tid];
  ((float4*)t_s)[tid + 256] = ((const float4*)g_t)[tid + 256];

  // sv[row] = exh[row] . w1a1 : 16 threads per row, 16 elems each
  {
    int row = tid >> 4, seg = tid & 15;
    const float* xsrc = exh + (size_t)(i0 + row) * 256 + seg * 16;
    const float* wsrc = g_w1a1 + seg * 16;
    float sp = 0.f;
#pragma unroll
    for (int j = 0; j < 4; ++j) {
      float4 x = *(const float4*)(xsrc + j * 4);
      float4 wv = *(const float4*)(wsrc + j * 4);
      sp += x.x * wv.x + x.y * wv.y + x.z * wv.z + x.w * wv.w;
    }
    sp += __shfl_xor(sp, 1, 64);
    sp += __shfl_xor(sp, 2, 64);
    sp += __shfl_xor(sp, 4, 64);
    sp += __shfl_xor(sp, 8, 64);
    if (seg == 0) sv_s[row] = sp;
  }
  __syncthreads();

  int r = lane & 15, g = lane >> 4;
  float sv = sv_s[r];
  const int* arow = adj + (size_t)(i0 + r) * N_KC;
  unsigned short* pb = g_P_pk + (size_t)blockIdx.x * 63 * 512 + lane * 8;
  float dsum = 0.f;

  // thread (r,g,q) owns kk = m*4+q : 16 fully independent iterations,
  // deep ILP, 128B-contiguous adj reads, 1KB-coalesced packed stores.
#pragma unroll
  for (int m = 0; m < 16; ++m) {
    int kk = m * 4 + q;
    if (kk < 63) {
      int c0 = kk * 32 + g * 8;
      int4 a0 = {0, 0, 0, 0}, a1 = {0, 0, 0, 0};
      if (c0 + 8 <= N_KC) {
        a0 = *(const int4*)(arow + c0);
        a1 = *(const int4*)(arow + c0 + 4);
      }
      float4 t0 = *(const float4*)(t_s + c0);
      float4 t1 = *(const float4*)(t_s + c0 + 4);
      float tv[8] = {t0.x, t0.y, t0.z, t0.w, t1.x, t1.y, t1.z, t1.w};
      int av[8] = {a0.x, a0.y, a0.z, a0.w, a1.x, a1.y, a1.z, a1.w};
      unsigned ub[8];
#pragma unroll
      for (int j = 0; j < 8; ++j) {
        float x = sv + tv[j];
        float lx = fmaxf(x, ALPHA * x);
        float pv = (av[j] > 0) ? __expf(lx) : 0.f;
        dsum += pv;
        ub[j] = __float_as_uint(pv) + 0x8000u;
      }
      int4 pk;
      pk.x = (int)((ub[0] >> 16) | (ub[1] & 0xFFFF0000u));
      pk.y = (int)((ub[2] >> 16) | (ub[3] & 0xFFFF0000u));
      pk.z = (int)((ub[4] >> 16) | (ub[5] & 0xFFFF0000u));
      pk.w = (int)((ub[6] >> 16) | (ub[7] & 0xFFFF0000u));
      *(int4*)(pb + (size_t)kk * 512) = pk;
    }
  }

  // denominator: sum over g (in-wave) then over q (LDS)
  dsum += __shfl_xor(dsum, 16, 64);
  dsum += __shfl_xor(dsum, 32, 64);
  if (lane < 16) ds_red[q][lane] = dsum;
  __syncthreads();
  if (tid < 16) {
    float s = ds_red[0][tid] + ds_red[1][tid] + ds_red[2][tid] + ds_red[3][tid];
    g_inv[i0 + tid] = 1.f / fmaxf(s, 1e-30f);
  }
}

// ---- G: pure GEMM pipeline. 313 blocks x 32 rows; K-loop is a clean
// 4-load + 4-MFMA stream (A from g_P_pk, B from g_kcWh_pk), zero barriers
// in-loop; then accE GEMM, feat, epilogue GEMM (3 barriers total).
#define FST 536  // feat row stride (shorts)
__global__ __launch_bounds__(512, 4) void g_gemm_kernel(
    const float* __restrict__ exh, const float* __restrict__ rd_b,
    float* __restrict__ out) {
  // exh_pk [2][8][512]u16 at 0 (16384B); feat [32][FST]u16 (34304B) overlays.
  __shared__ __align__(16) unsigned char smem[34816];
  __shared__ float inv_s[32];
  unsigned short* exh_pk_s = (unsigned short*)smem;
  unsigned short* feat_s = (unsigned short*)smem;

  int tid = threadIdx.x, w = tid >> 6, lane = tid & 63;
  int r = lane & 15, g = lane >> 4;
  int i0 = blockIdx.x * 32;

  // phase 0: stage exh fragments + per-row inverse denominators
  {
#pragma unroll
    for (int m = 0; m < 2; ++m) {
      int row = i0 + m * 16 + r; row = row < N_E ? row : N_E - 1;
      const float* xsrc = exh + (size_t)row * 256 + w * 32 + g * 8;
      float4 x0 = *(const float4*)xsrc, x1 = *(const float4*)(xsrc + 4);
      unsigned short* dst = exh_pk_s + m * 4096 + w * 512 + lane * 8;
      cvt_store4(x0, dst); cvt_store4(x1, dst + 4);
    }
  }
  if (tid < 32) {
    int row = i0 + tid;
    inv_s[tid] = g_inv[row < N_E ? row : 0];
  }

  // K-loop: barrier-free dual stream. Wave w owns col-tiles 2w, 2w+1.
  f32x4 accP[2][2] = {{{0.f,0.f,0.f,0.f},{0.f,0.f,0.f,0.f}},
                      {{0.f,0.f,0.f,0.f},{0.f,0.f,0.f,0.f}}};
  const unsigned short* pa0 =
      g_P_pk + (size_t)(blockIdx.x * 2 + 0) * 63 * 512 + lane * 8;
  const unsigned short* pa1 =
      g_P_pk + (size_t)(blockIdx.x * 2 + 1) * 63 * 512 + lane * 8;  // tile 625 = BSS-zero phantom for b=312
  const unsigned short* bb0 =
      g_kcWh_pk + (size_t)(w * 2 + 0) * 64 * 512 + lane * 8;
  const unsigned short* bb1 =
      g_kcWh_pk + (size_t)(w * 2 + 1) * 64 * 512 + lane * 8;
#pragma unroll 7
  for (int kk = 0; kk < 63; ++kk) {
    short8 a0 = *(const short8*)(pa0 + (size_t)kk * 512);
    short8 a1 = *(const short8*)(pa1 + (size_t)kk * 512);
    short8 b0 = *(const short8*)(bb0 + (size_t)kk * 512);
    short8 b1 = *(const short8*)(bb1 + (size_t)kk * 512);
    accP[0][0] = __builtin_amdgcn_mfma_f32_16x16x32_bf16(a0, b0, accP[0][0], 0, 0, 0);
    accP[1][0] = __builtin_amdgcn_mfma_f32_16x16x32_bf16(a1, b0, accP[1][0], 0, 0, 0);
    accP[0][1] = __builtin_amdgcn_mfma_f32_16x16x32_bf16(a0, b1, accP[0][1], 0, 0, 0);
    accP[1][1] = __builtin_amdgcn_mfma_f32_16x16x32_bf16(a1, b1, accP[1][1], 0, 0, 0);
  }

  __syncthreads();  // exh_pk staged (all waves) before cross-wave accE reads

  // ---- ex_Eh GEMM ----
  f32x4 accE[2][2] = {{{0.f,0.f,0.f,0.f},{0.f,0.f,0.f,0.f}},
                      {{0.f,0.f,0.f,0.f},{0.f,0.f,0.f,0.f}}};
#pragma unroll
  for (int kk = 0; kk < 8; ++kk) {
    short8 a0 = *(const short8*)(exh_pk_s + kk * 512 + lane * 8);
    short8 a1 = *(const short8*)(exh_pk_s + 4096 + kk * 512 + lane * 8);
#pragma unroll
    for (int n = 0; n < 2; ++n) {
      short8 bf = *(const short8*)(g_ET_pk + ((size_t)(w * 2 + n) * 8 + kk) *
                                                 512 + lane * 8);
      accE[0][n] = __builtin_amdgcn_mfma_f32_16x16x32_bf16(a0, bf, accE[0][n], 0, 0, 0);
      accE[1][n] = __builtin_amdgcn_mfma_f32_16x16x32_bf16(a1, bf, accE[1][n], 0, 0, 0);
    }
  }
  __syncthreads();  // all waves done reading exh_pk before feat overlay

  // ---- feat = [new_kc | new_kc * ex_Eh] ----
  int c0e = w * 32;
#pragma unroll
  for (int m = 0; m < 2; ++m)
#pragma unroll
    for (int n = 0; n < 2; ++n) {
      int col = c0e + n * 16 + r;
#pragma unroll
      for (int q2 = 0; q2 < 4; ++q2) {
        int row = m * 16 + g * 4 + q2;
        float nk = accP[m][n][q2] * inv_s[row];
        feat_s[(size_t)row * FST + col] = f2bf(nk);
        feat_s[(size_t)row * FST + 256 + col] = f2bf(nk * accE[m][n][q2]);
      }
    }
  __syncthreads();

  // ---- epilogue GEMM: feat(32x512) @ rd_w^T + bias, ELU ----
  f32x4 accO[2][2] = {{{0.f,0.f,0.f,0.f},{0.f,0.f,0.f,0.f}},
                      {{0.f,0.f,0.f,0.f},{0.f,0.f,0.f,0.f}}};
#pragma unroll
  for (int kt = 0; kt < 16; ++kt) {
    int k = kt * 32 + g * 8;
    short8 a0 = *(const short8*)(feat_s + (size_t)r * FST + k);
    short8 a1 = *(const short8*)(feat_s + (size_t)(16 + r) * FST + k);
#pragma unroll
    for (int n = 0; n < 2; ++n) {
      short8 bf = *(const short8*)(g_rdw_pk + ((size_t)(w * 2 + n) * 16 + kt) *
                                                  512 + lane * 8);
      accO[0][n] = __builtin_amdgcn_mfma_f32_16x16x32_bf16(a0, bf, accO[0][n], 0, 0, 0);
      accO[1][n] = __builtin_amdgcn_mfma_f32_16x16x32_bf16(a1, bf, accO[1][n], 0, 0, 0);
    }
  }
#pragma unroll
  for (int m = 0; m < 2; ++m) {
    if (i0 + m * 16 >= N_E) continue;
#pragma unroll
    for (int n = 0; n < 2; ++n) {
      int col = c0e + n * 16 + r;
      float bias = rd_b[col];
#pragma unroll
      for (int q2 = 0; q2 < 4; ++q2) {
        int row = i0 + m * 16 + g * 4 + q2;
        float x = accO[m][n][q2] + bias;
        float res = x > 0.f ? x : (__expf(x) - 1.f);
        out[(size_t)row * 256 + col] = res;
      }
    }
  }
}

extern "C" void kernel_launch(void* const* d_in, const int* in_sizes, int n_in,
                              void* d_out, int out_size, void* d_ws,
                              size_t ws_size, hipStream_t stream) {
  const float* exh  = (const float*)d_in[0];
  const float* kc_h = (const float*)d_in[1];
  const int*   adj  = (const int*)d_in[2];
  const float* W1   = (const float*)d_in[3];
  const float* E    = (const float*)d_in[4];
  const float* a    = (const float*)d_in[5];
  const float* rd_w = (const float*)d_in[6];
  const float* rd_b = (const float*)d_in[7];
  float* out = (float*)d_out;

  prep_kernel<<<66, 256, 0, stream>>>(W1, E, a, rd_w);
  kc_mfma_kernel<<<N_KC / 16, 256, 0, stream>>>(kc_h, a);
  p_gen_kernel<<<N_E / 16, 256, 0, stream>>>(exh, adj);
  g_gemm_kernel<<<(N_E + 31) / 32, 512, 0, stream>>>(exh, rd_b, out);
}